// Round 6
// baseline (82.033 us; speedup 1.0000x reference)
//
#include <hip/hip_runtime.h>
#include <hip/hip_bf16.h>
#include <cstdint>

typedef unsigned short u16;
typedef unsigned int u32;
typedef __attribute__((ext_vector_type(8))) short short8;   // 8 bf16 (4 VGPRs) MFMA A/B frag
typedef __attribute__((ext_vector_type(4))) float f32x4;    // MFMA C/D frag
typedef __attribute__((ext_vector_type(4))) unsigned int u32x4;
typedef __attribute__((ext_vector_type(4))) unsigned short u16x4;

#define REV 15.91549431f   // 100/(2*pi): converts the "100*pos" angle to revolutions

// ---------- helpers ----------
__device__ __forceinline__ u16 f2b(float x) {               // f32 -> bf16 bits (HW RNE cvt)
    return __builtin_bit_cast(u16, (__bf16)x);
}
__device__ __forceinline__ u16 f2h(float x) {               // f32 -> f16 bits (HW cvt)
    return __builtin_bit_cast(u16, (_Float16)x);
}

__device__ __forceinline__ float c_dim_f(int f) {
    const float c[8] = {1.0f, 0.42169650f, 0.17782794f, 0.074989421f,
                        0.031622777f, 0.013335214f, 0.0056234132f, 0.0023713737f};
    return c[f];
}

// ---------- f32 -> bf16 conversion + per-box trig table ----------
// z 0..2: X inputs (1,048,576 els each) -> dstX + z*1048576
// z 3..6: weights  (262,144 els each)  -> dstW + (z-3)*262144
// z 7   : per-box table TB[box][32] f32 = {sin(aw_f) x8, cos(aw_f) x8,
//          sin(ah_f) x8, cos(ah_f) x8}, aw_f = log(w)*REV*c_dim[f] (revolutions)
__global__ __launch_bounds__(256) void cvt_k(const float* __restrict__ s0,
                                             const float* __restrict__ s1,
                                             const float* __restrict__ s2,
                                             const float* __restrict__ s3,
                                             const float* __restrict__ s4,
                                             const float* __restrict__ s5,
                                             const float* __restrict__ s6,
                                             const float* __restrict__ box,
                                             u16* __restrict__ dstX,
                                             u16* __restrict__ dstW,
                                             float* __restrict__ TB) {
    const int z = blockIdx.z;
    if (z == 7) {
        if (blockIdx.x >= 8) return;
        int gid = blockIdx.x * 256 + threadIdx.x;          // 0..2047 boxes
        float4 bx = *(const float4*)&box[(size_t)gid * 4];
        float w = bx.z - bx.x + 1.0f, h = bx.w - bx.y + 1.0f;
        float lw = __logf(w) * REV, lh = __logf(h) * REV;
        float* T = TB + (size_t)gid * 32;
#pragma unroll
        for (int f = 0; f < 8; f++) {
            float aw = lw * c_dim_f(f), ah = lh * c_dim_f(f);
            T[f]      = __builtin_amdgcn_sinf(aw);
            T[8 + f]  = __builtin_amdgcn_cosf(aw);
            T[16 + f] = __builtin_amdgcn_sinf(ah);
            T[24 + f] = __builtin_amdgcn_cosf(ah);
        }
        return;
    }
    const float* s;
    u16* dst;
    if (z < 3) {
        s = (z == 0) ? s0 : (z == 1) ? s1 : s2;
        dst = dstX + (size_t)z * 1048576;
    } else {
        if (blockIdx.x >= 256) return;
        s = (z == 3) ? s3 : (z == 4) ? s4 : (z == 5) ? s5 : s6;
        dst = dstW + (size_t)(z - 3) * 262144;
    }
    int i = (blockIdx.x * 256 + threadIdx.x) * 4;
    float4 v = *(const float4*)&s[i];
    u16x4 o = { f2b(v.x), f2b(v.y), f2b(v.z), f2b(v.w) };
    *(u16x4*)&dst[i] = o;
}

// ---------- geometry weight: w = 1024*max(relu(emb@WG+bG),1e-6) as f16 ----------
// p=0,1 (delta_x/delta_y): per-pair v_sin/v_cos (non-separable).
// p=2,3 (delta_w/delta_h): separable! sin(a_i - a_j) = s_i*c_j - c_i*s_j from
// the per-box table TB -> 64 FMA replace 32 transcendentals + 4 logs per pair.
__global__ __launch_bounds__(256) void geom_k(const float* __restrict__ box,
                                              const float* __restrict__ WG,
                                              const float* __restrict__ bG,
                                              const float* __restrict__ TB,
                                              u16* __restrict__ outW) {
    __shared__ char embs[256 * 128];   // [256 pairs][64 bf16] rows, 128B each

    const int t = threadIdx.x;
    const int wave = t >> 6, lane = t & 63;
    const int jt = blockIdx.x, i = blockIdx.y, b = blockIdx.z;
    const int j = (jt << 8) + t;
    const int swz = (t & 7) << 4;

    float4 bi = *(const float4*)&box[(size_t)(((b << 9) + i) << 2)];
    float4 bj = *(const float4*)&box[(size_t)(((b << 9) + j) << 2)];
    float cxi = (bi.x + bi.z) * 0.5f, cyi = (bi.y + bi.w) * 0.5f;
    float wi = bi.z - bi.x + 1.0f,    hgt_i = bi.w - bi.y + 1.0f;
    float cxj = (bj.x + bj.z) * 0.5f, cyj = (bj.y + bj.w) * 0.5f;

    float pos01[2];
    pos01[0] = __logf(fmaxf(fabsf((cxi - cxj) / wi), 1e-3f));
    pos01[1] = __logf(fmaxf(fabsf((cyi - cyj) / hgt_i), 1e-3f));

    // ---- p = 0,1: direct trig (revolutions, |rev| <= ~112 < HW domain) ----
#pragma unroll
    for (int p = 0; p < 2; p++) {
        float rev = pos01[p] * REV;
        u32x4 sp, cp;
#pragma unroll
        for (int f = 0; f < 4; f++) {
            float a0 = rev * c_dim_f(2 * f), a1 = rev * c_dim_f(2 * f + 1);
            sp[f] = (u32)f2b(__builtin_amdgcn_sinf(a0)) | ((u32)f2b(__builtin_amdgcn_sinf(a1)) << 16);
            cp[f] = (u32)f2b(__builtin_amdgcn_cosf(a0)) | ((u32)f2b(__builtin_amdgcn_cosf(a1)) << 16);
        }
        *(u32x4*)(embs + (((t << 7) + (p << 4)) ^ swz)) = sp;
        *(u32x4*)(embs + (((t << 7) + 64 + (p << 4)) ^ swz)) = cp;
    }

    // ---- p = 2,3: angle-difference from per-box table ----
    const float* Ti = TB + (size_t)(((b << 9) + i) << 5);   // block-uniform
    const float* Tj = TB + (size_t)(((b << 9) + j) << 5);   // per-lane
#pragma unroll
    for (int p = 2; p < 4; p++) {
        const int o = (p - 2) << 4;
        float4 sj0 = *(const float4*)&Tj[o],     sj1 = *(const float4*)&Tj[o + 4];
        float4 cj0 = *(const float4*)&Tj[o + 8], cj1 = *(const float4*)&Tj[o + 12];
        float sjv[8] = {sj0.x, sj0.y, sj0.z, sj0.w, sj1.x, sj1.y, sj1.z, sj1.w};
        float cjv[8] = {cj0.x, cj0.y, cj0.z, cj0.w, cj1.x, cj1.y, cj1.z, cj1.w};
        u32x4 sp, cp;
#pragma unroll
        for (int f = 0; f < 4; f++) {
            float si0 = Ti[o + 2 * f], si1 = Ti[o + 2 * f + 1];
            float ci0 = Ti[o + 8 + 2 * f], ci1 = Ti[o + 8 + 2 * f + 1];
            float s0 = si0 * cjv[2 * f]     - ci0 * sjv[2 * f];
            float s1 = si1 * cjv[2 * f + 1] - ci1 * sjv[2 * f + 1];
            float c0 = ci0 * cjv[2 * f]     + si0 * sjv[2 * f];
            float c1 = ci1 * cjv[2 * f + 1] + si1 * sjv[2 * f + 1];
            sp[f] = (u32)f2b(s0) | ((u32)f2b(s1) << 16);
            cp[f] = (u32)f2b(c0) | ((u32)f2b(c1) << 16);
        }
        *(u32x4*)(embs + (((t << 7) + (p << 4)) ^ swz)) = sp;
        *(u32x4*)(embs + (((t << 7) + 64 + (p << 4)) ^ swz)) = cp;
    }

    const int h = lane & 15;
    const int ko = (lane >> 4) << 3;
    short8 bf0 = {0, 0, 0, 0, 0, 0, 0, 0};
    short8 bf1 = {0, 0, 0, 0, 0, 0, 0, 0};
    float bGh = 0.0f;
    if (h < 8) {
        const float* wrow = WG + h * 64;
#pragma unroll
        for (int e = 0; e < 8; e++) {
            bf0[e] = (short)f2b(wrow[ko + e]);
            bf1[e] = (short)f2b(wrow[32 + ko + e]);
        }
        bGh = bG[h];
    }
    __syncthreads();

#pragma unroll
    for (int tt = 0; tt < 4; tt++) {
        int mt = (wave << 2) + tt;
        int row = (mt << 4) + h;
        int rswz = (row & 7) << 4;
        short8 a0 = *(const short8*)(embs + (((row << 7) + (ko << 1)) ^ rswz));
        short8 a1 = *(const short8*)(embs + (((row << 7) + 64 + (ko << 1)) ^ rswz));
        f32x4 acc = {0.f, 0.f, 0.f, 0.f};
        acc = __builtin_amdgcn_mfma_f32_16x16x32_bf16(a0, bf0, acc, 0, 0, 0);
        acc = __builtin_amdgcn_mfma_f32_16x16x32_bf16(a1, bf1, acc, 0, 0, 0);

        if (h < 8) {
            int j0 = (jt << 8) + (mt << 4) + ((lane >> 4) << 2);
            u16x4 ow;
#pragma unroll
            for (int r = 0; r < 4; r++)
                ow[r] = f2h(fmaxf(acc[r] + bGh, 1e-6f) * 1024.0f);
            *(u16x4*)&outW[((size_t)((b << 3) + h) << 18) + ((size_t)i << 9) + j0] = ow;
        }
    }
}

// ---------- fused flash attention: p = w * e^(0.125*QK^T - m), O = PV/l ----------
__global__ __launch_bounds__(256) void attn_k(const u16* __restrict__ Qb,
                                              const u16* __restrict__ Kb,
                                              const u16* __restrict__ VT,
                                              const u16* __restrict__ Wp,
                                              u16* __restrict__ ATT) {
    __shared__ u16 Pl[4][16 * 68];       // per-wave P transpose, stride 68
    __shared__ float Mrg[3][64][25];     // waves 1-3 partials: m[0:4] l[4:8] o[8:24], pad 25
    const int t = threadIdx.x;
    const int wave = t >> 6, lane = t & 63;
    const int c = lane & 15, g = lane >> 4;
    const int bid = blockIdx.x;
    const int qb = bid & 31, bh = bid >> 5;
    const int b = bh >> 3, h = bh & 7;
    const int q0 = qb << 4;

    const u16* Qp = Qb + ((size_t)bh << 15);                 // [512][64]
    const u16* Kp = Kb + ((size_t)bh << 15);                 // [512][64]
    const u16* Vp = VT + ((size_t)bh << 15);                 // [64][512]
    const _Float16* Bp = (const _Float16*)Wp + ((size_t)bh << 18) + ((size_t)q0 << 9);

    short8 qf[2];
#pragma unroll
    for (int ks = 0; ks < 2; ks++)
        qf[ks] = *(const short8*)&Qp[(size_t)(q0 + c) * 64 + ks * 32 + g * 8];

    f32x4 o[4] = {};
    float m[4] = {-1e30f, -1e30f, -1e30f, -1e30f};
    float l[4] = {0.f, 0.f, 0.f, 0.f};

    for (int kt = 0; kt < 2; kt++) {
        const int k0 = ((wave << 1) + kt) << 6;
        short8 kf[4][2], vf[4][2];
#pragma unroll
        for (int jj = 0; jj < 4; jj++)
#pragma unroll
            for (int ks = 0; ks < 2; ks++) {
                kf[jj][ks] = *(const short8*)&Kp[(size_t)(k0 + jj * 16 + c) * 64 + ks * 32 + g * 8];
                vf[jj][ks] = *(const short8*)&Vp[(size_t)(jj * 16 + c) * 512 + k0 + ks * 32 + g * 8];
            }
        float wgt[4][4];
#pragma unroll
        for (int jj = 0; jj < 4; jj++)
#pragma unroll
            for (int r = 0; r < 4; r++)
                wgt[jj][r] = (float)Bp[(size_t)(g * 4 + r) * 512 + k0 + jj * 16 + c];

        f32x4 sa[4] = {};
        __builtin_amdgcn_s_setprio(1);
#pragma unroll
        for (int jj = 0; jj < 4; jj++)
#pragma unroll
            for (int ks = 0; ks < 2; ks++)
                sa[jj] = __builtin_amdgcn_mfma_f32_16x16x32_bf16(qf[ks], kf[jj][ks], sa[jj], 0, 0, 0);
        __builtin_amdgcn_s_setprio(0);

        float s[4][4];
#pragma unroll
        for (int r = 0; r < 4; r++) {
#pragma unroll
            for (int jj = 0; jj < 4; jj++)
                s[jj][r] = sa[jj][r] * 0.125f;
            float v = fmaxf(fmaxf(s[0][r], s[1][r]), fmaxf(s[2][r], s[3][r]));
#pragma unroll
            for (int off = 1; off < 16; off <<= 1)
                v = fmaxf(v, __shfl_xor(v, off));
            float mn = fmaxf(m[r], v);
            float alpha = __expf(m[r] - mn);
            m[r] = mn;
            float rs = 0.f;
#pragma unroll
            for (int jj = 0; jj < 4; jj++) {
                float p = wgt[jj][r] * __expf(s[jj][r] - mn);
                s[jj][r] = p;
                rs += p;
            }
#pragma unroll
            for (int off = 1; off < 16; off <<= 1)
                rs += __shfl_xor(rs, off);
            l[r] = l[r] * alpha + rs;
#pragma unroll
            for (int jjo = 0; jjo < 4; jjo++)
                o[jjo][r] *= alpha;
        }

#pragma unroll
        for (int jj = 0; jj < 4; jj++)
#pragma unroll
            for (int r = 0; r < 4; r++)
                Pl[wave][(g * 4 + r) * 68 + jj * 16 + c] = f2b(s[jj][r]);
        asm volatile("s_waitcnt lgkmcnt(0)" ::: "memory");
        __builtin_amdgcn_sched_barrier(0);

        short8 pa[2];
#pragma unroll
        for (int ks = 0; ks < 2; ks++)
            pa[ks] = *(const short8*)&Pl[wave][c * 68 + ks * 32 + g * 8];
        __builtin_amdgcn_s_setprio(1);
#pragma unroll
        for (int jjo = 0; jjo < 4; jjo++)
#pragma unroll
            for (int ks = 0; ks < 2; ks++)
                o[jjo] = __builtin_amdgcn_mfma_f32_16x16x32_bf16(pa[ks], vf[jjo][ks], o[jjo], 0, 0, 0);
        __builtin_amdgcn_s_setprio(0);
        __builtin_amdgcn_sched_barrier(0);
    }

    if (wave > 0) {
#pragma unroll
        for (int r = 0; r < 4; r++) {
            Mrg[wave - 1][lane][r] = m[r];
            Mrg[wave - 1][lane][4 + r] = l[r];
#pragma unroll
            for (int jjo = 0; jjo < 4; jjo++)
                Mrg[wave - 1][lane][8 + jjo * 4 + r] = o[jjo][r];
        }
    }
    __syncthreads();
    if (wave == 0) {
#pragma unroll
        for (int w = 0; w < 3; w++) {
#pragma unroll
            for (int r = 0; r < 4; r++) {
                float m1 = Mrg[w][lane][r];
                float l1 = Mrg[w][lane][4 + r];
                float mn = fmaxf(m[r], m1);
                float a0 = __expf(m[r] - mn), a1 = __expf(m1 - mn);
                m[r] = mn;
                l[r] = l[r] * a0 + l1 * a1;
#pragma unroll
                for (int jjo = 0; jjo < 4; jjo++)
                    o[jjo][r] = o[jjo][r] * a0 + Mrg[w][lane][8 + jjo * 4 + r] * a1;
            }
        }
#pragma unroll
        for (int r = 0; r < 4; r++) {
            float inv = 1.0f / l[r];
            int row = q0 + g * 4 + r;
#pragma unroll
            for (int jjo = 0; jjo < 4; jjo++)
                ATT[(size_t)(((b << 9) + row) << 9) + (h << 6) + jjo * 16 + c] = f2b(o[jjo][r] * inv);
        }
    }
}

// ---------- merged projection GEMM (bf16 LDS-staged MFMA) ----------
// z=0: Q, z=1: K (out [B,H,N,DK]); z=2: V (out transposed [B,H,DK,N]).
__global__ __launch_bounds__(256) void proj_k(const u16* __restrict__ Xall,
                                              const u16* __restrict__ Wall,
                                              const float* __restrict__ bq,
                                              const float* __restrict__ bk,
                                              const float* __restrict__ bv,
                                              u16* __restrict__ Qb,
                                              u16* __restrict__ Kb,
                                              u16* __restrict__ VT) {
    __shared__ u16 As[64 * 32];
    __shared__ u16 Bs[64 * 32];

    const int t = threadIdx.x;
    const int wave = t >> 6, lane = t & 63;
    const int wr = wave >> 1, wc = wave & 1;
    const int m0 = blockIdx.y * 64, n0 = blockIdx.x * 64;
    const int z = blockIdx.z;

    const u16* A  = Xall + (size_t)z * 1048576;
    const u16* Bm = Wall + (size_t)z * 262144;
    const float* bias = (z == 0) ? bq : (z == 1) ? bk : bv;
    u16* out = (z == 0) ? Qb : (z == 1) ? Kb : VT;

    f32x4 acc[2][2] = {};
    const int srow = t >> 2, scol = (t & 3) * 8;

    for (int k0 = 0; k0 < 512; k0 += 32) {
        *(u32x4*)&As[srow * 32 + scol] = *(const u32x4*)&A[(size_t)(m0 + srow) * 512 + k0 + scol];
        *(u32x4*)&Bs[srow * 32 + scol] = *(const u32x4*)&Bm[(size_t)(n0 + srow) * 512 + k0 + scol];
        __syncthreads();

        short8 af[2], bfr[2];
#pragma unroll
        for (int i = 0; i < 2; i++)
            af[i] = *(const short8*)&As[(wr * 32 + i * 16 + (lane & 15)) * 32 + ((lane >> 4) << 3)];
#pragma unroll
        for (int jj = 0; jj < 2; jj++)
            bfr[jj] = *(const short8*)&Bs[(wc * 32 + jj * 16 + (lane & 15)) * 32 + ((lane >> 4) << 3)];
#pragma unroll
        for (int i = 0; i < 2; i++)
#pragma unroll
            for (int jj = 0; jj < 2; jj++)
                acc[i][jj] = __builtin_amdgcn_mfma_f32_16x16x32_bf16(af[i], bfr[jj], acc[i][jj], 0, 0, 0);
        __syncthreads();
    }

#pragma unroll
    for (int i = 0; i < 2; i++) {
#pragma unroll
        for (int jj = 0; jj < 2; jj++) {
#pragma unroll
            for (int r = 0; r < 4; r++) {
                int row = m0 + wr * 32 + i * 16 + ((lane >> 4) << 2) + r;
                int col = n0 + wc * 32 + jj * 16 + (lane & 15);
                float v = acc[i][jj][r] + bias[col];
                int b = row >> 9, rr = row & 511, h = col >> 6, d = col & 63;
                if (z < 2)
                    out[(size_t)((((b << 3) + h) << 9) + rr) * 64 + d] = f2b(v);
                else
                    out[(size_t)((((b << 3) + h) << 6) + d) * 512 + rr] = f2b(v);
            }
        }
    }
}

// ---------- output GEMM: d_out[2048,512] f32 = ATT bf16 @ WOb^T + bo ----------
__global__ __launch_bounds__(256) void outg_k(const u16* __restrict__ A,
                                              const u16* __restrict__ Bm,
                                              const float* __restrict__ bias,
                                              float* __restrict__ outF) {
    __shared__ u16 As[64 * 32];
    __shared__ u16 Bs[64 * 32];

    const int t = threadIdx.x;
    const int wave = t >> 6, lane = t & 63;
    const int wr = wave >> 1, wc = wave & 1;
    const int m0 = blockIdx.y * 64, n0 = blockIdx.x * 64;

    f32x4 acc[2][2] = {};
    const int srow = t >> 2, scol = (t & 3) * 8;

    for (int k0 = 0; k0 < 512; k0 += 32) {
        *(u32x4*)&As[srow * 32 + scol] = *(const u32x4*)&A[(size_t)(m0 + srow) * 512 + k0 + scol];
        *(u32x4*)&Bs[srow * 32 + scol] = *(const u32x4*)&Bm[(size_t)(n0 + srow) * 512 + k0 + scol];
        __syncthreads();

        short8 af[2], bfr[2];
#pragma unroll
        for (int i = 0; i < 2; i++)
            af[i] = *(const short8*)&As[(wr * 32 + i * 16 + (lane & 15)) * 32 + ((lane >> 4) << 3)];
#pragma unroll
        for (int jj = 0; jj < 2; jj++)
            bfr[jj] = *(const short8*)&Bs[(wc * 32 + jj * 16 + (lane & 15)) * 32 + ((lane >> 4) << 3)];
#pragma unroll
        for (int i = 0; i < 2; i++)
#pragma unroll
            for (int jj = 0; jj < 2; jj++)
                acc[i][jj] = __builtin_amdgcn_mfma_f32_16x16x32_bf16(af[i], bfr[jj], acc[i][jj], 0, 0, 0);
        __syncthreads();
    }

#pragma unroll
    for (int i = 0; i < 2; i++)
#pragma unroll
        for (int jj = 0; jj < 2; jj++)
#pragma unroll
            for (int r = 0; r < 4; r++) {
                int row = m0 + wr * 32 + i * 16 + ((lane >> 4) << 2) + r;
                int col = n0 + wc * 32 + jj * 16 + (lane & 15);
                outF[((size_t)row << 9) + col] = acc[i][jj][r] + bias[col];
            }
}

// ---------- launch ----------
extern "C" void kernel_launch(void* const* d_in, const int* in_sizes, int n_in,
                              void* d_out, int out_size, void* d_ws, size_t ws_size,
                              hipStream_t stream) {
    const float* inq = (const float*)d_in[0];
    const float* ink = (const float*)d_in[1];
    const float* inv = (const float*)d_in[2];
    const float* box = (const float*)d_in[3];
    const float* Wq  = (const float*)d_in[4];
    const float* bq  = (const float*)d_in[5];
    const float* Wk  = (const float*)d_in[6];
    const float* bk  = (const float*)d_in[7];
    const float* Wv  = (const float*)d_in[8];
    const float* bv  = (const float*)d_in[9];
    const float* Wo  = (const float*)d_in[10];
    const float* bo  = (const float*)d_in[11];
    const float* WG  = (const float*)d_in[12];
    const float* bG  = (const float*)d_in[13];

    u16* base = (u16*)d_ws;
    u16* Xall = base;                    // XQ,XK,XV bf16 (3 x 1,048,576)
    u16* Wall = base + 3145728;          // WQb,WKb,WVb,WOb bf16 (4 x 262,144)
    u16* Qb   = base + 4194304;          // [B,H,N,64] bf16
    u16* Kb   = base + 5242880;          // [B,H,N,64] bf16
    u16* VT   = base + 6291456;          // [B,H,64,N] bf16
    u16* ATT  = base + 7340032;          // [B,N,512] bf16
    u16* Wp   = base + 8388608;          // [B,H,N,N] f16 geometry weights (8,388,608 u16)
    float* TB = (float*)(base + 16777216); // per-box trig table [2048][32] f32 (256 KB)

    cvt_k<<<dim3(1024, 1, 8), 256, 0, stream>>>(inq, ink, inv, Wq, Wk, Wv, Wo, box,
                                                Xall, Wall, TB);
    geom_k<<<dim3(2, 512, 4), 256, 0, stream>>>(box, WG, bG, TB, Wp);

    proj_k<<<dim3(8, 32, 3), 256, 0, stream>>>(Xall, Wall, bq, bk, bv, Qb, Kb, VT);

    attn_k<<<dim3(1024), 256, 0, stream>>>(Qb, Kb, VT, Wp, ATT);

    outg_k<<<dim3(8, 32, 1), 256, 0, stream>>>(ATT, Wall + 786432, bo, (float*)d_out);
}

// Round 7
// 70.499 us; speedup vs baseline: 1.1636x; 1.1636x over previous
//
#include <hip/hip_runtime.h>
#include <hip/hip_bf16.h>
#include <cstdint>

typedef unsigned short u16;
typedef unsigned int u32;
typedef __attribute__((ext_vector_type(8))) short short8;   // 8 bf16 (4 VGPRs) MFMA A/B frag
typedef __attribute__((ext_vector_type(4))) float f32x4;    // MFMA C/D frag
typedef __attribute__((ext_vector_type(4))) unsigned int u32x4;
typedef __attribute__((ext_vector_type(4))) unsigned short u16x4;

#define REV 15.91549431f   // 100/(2*pi): the "100*pos" angle in revolutions

// ---------- helpers ----------
__device__ __forceinline__ u16 f2b(float x) {               // f32 -> bf16 bits (HW RNE cvt)
    return __builtin_bit_cast(u16, (__bf16)x);
}
__device__ __forceinline__ u16 f2h(float x) {               // f32 -> f16 bits (HW cvt)
    return __builtin_bit_cast(u16, (_Float16)x);
}
__device__ __forceinline__ float c_dim_f(int f) {
    const float c[8] = {1.0f, 0.42169650f, 0.17782794f, 0.074989421f,
                        0.031622777f, 0.013335214f, 0.0056234132f, 0.0023713737f};
    return c[f];
}
// async global->LDS, 16B per lane (dest = wave-uniform base + lane*16)
__device__ __forceinline__ void gload_lds16(const void* g, void* l) {
    __builtin_amdgcn_global_load_lds((const __attribute__((address_space(1))) u32*)g,
                                     (__attribute__((address_space(3))) u32*)l, 16, 0, 0);
}

// ---------- prep: f32->bf16 cvt (z 0..6) + geometry weights (z 7..10) ----------
// z 0..2: X inputs (1,048,576 els) -> Xall + z*1048576
// z 3..6: weights  (262,144 els)   -> Wall + (z-3)*262144   [blockIdx.x < 256]
// z 7..10: geom for b = z-7; blockIdx.x -> jt = x&1, i = x>>1.
//   w = 1024*max(relu(emb@WG+bG),1e-6) stored f16 (consumed multiplicatively:
//   softmax(log(w)+s) == normalized w*e^s; *1024 exact scale avoids subnormals).
__global__ __launch_bounds__(256) void prep_k(const float* __restrict__ s0,
                                              const float* __restrict__ s1,
                                              const float* __restrict__ s2,
                                              const float* __restrict__ s3,
                                              const float* __restrict__ s4,
                                              const float* __restrict__ s5,
                                              const float* __restrict__ s6,
                                              const float* __restrict__ box,
                                              const float* __restrict__ WG,
                                              const float* __restrict__ bG,
                                              u16* __restrict__ dstX,
                                              u16* __restrict__ dstW,
                                              u16* __restrict__ outW) {
    __shared__ char embs[256 * 128];   // [256 pairs][64 bf16] rows, 128B each
    const int z = blockIdx.z;
    const int t = threadIdx.x;

    if (z < 7) {
        const float* s;
        u16* dst;
        if (z < 3) {
            s = (z == 0) ? s0 : (z == 1) ? s1 : s2;
            dst = dstX + (size_t)z * 1048576;
        } else {
            if (blockIdx.x >= 256) return;
            s = (z == 3) ? s3 : (z == 4) ? s4 : (z == 5) ? s5 : s6;
            dst = dstW + (size_t)(z - 3) * 262144;
        }
        int i = (blockIdx.x * 256 + t) * 4;
        float4 v = *(const float4*)&s[i];
        u16x4 o = { f2b(v.x), f2b(v.y), f2b(v.z), f2b(v.w) };
        *(u16x4*)&dst[i] = o;
        return;
    }

    // ---------------- geometry ----------------
    const int wave = t >> 6, lane = t & 63;
    const int b = z - 7;
    const int jt = blockIdx.x & 1, i = blockIdx.x >> 1;
    const int j = (jt << 8) + t;
    const int swz = (t & 7) << 4;

    float4 bi = *(const float4*)&box[(size_t)(((b << 9) + i) << 2)];
    float4 bj = *(const float4*)&box[(size_t)(((b << 9) + j) << 2)];
    float cxi = (bi.x + bi.z) * 0.5f, cyi = (bi.y + bi.w) * 0.5f;
    float wi = bi.z - bi.x + 1.0f,    hgt_i = bi.w - bi.y + 1.0f;
    float cxj = (bj.x + bj.z) * 0.5f, cyj = (bj.y + bj.w) * 0.5f;
    float wj = bj.z - bj.x + 1.0f,    hgt_j = bj.w - bj.y + 1.0f;

    float pos[4];
    pos[0] = __logf(fmaxf(fabsf((cxi - cxj) / wi), 1e-3f));
    pos[1] = __logf(fmaxf(fabsf((cyi - cyj) / hgt_i), 1e-3f));
    pos[2] = __logf(wi) - __logf(wj);
    pos[3] = __logf(hgt_i) - __logf(hgt_j);

#pragma unroll
    for (int p = 0; p < 4; p++) {
        float rev = pos[p] * REV;
        u32x4 sp, cp;
#pragma unroll
        for (int f = 0; f < 4; f++) {
            float a0 = rev * c_dim_f(2 * f), a1 = rev * c_dim_f(2 * f + 1);
            sp[f] = (u32)f2b(__builtin_amdgcn_sinf(a0)) | ((u32)f2b(__builtin_amdgcn_sinf(a1)) << 16);
            cp[f] = (u32)f2b(__builtin_amdgcn_cosf(a0)) | ((u32)f2b(__builtin_amdgcn_cosf(a1)) << 16);
        }
        *(u32x4*)(embs + (((t << 7) + (p << 4)) ^ swz)) = sp;
        *(u32x4*)(embs + (((t << 7) + 64 + (p << 4)) ^ swz)) = cp;
    }

    const int h = lane & 15;
    const int ko = (lane >> 4) << 3;
    short8 bf0 = {0, 0, 0, 0, 0, 0, 0, 0};
    short8 bf1 = {0, 0, 0, 0, 0, 0, 0, 0};
    float bGh = 0.0f;
    if (h < 8) {
        const float* wrow = WG + h * 64;
#pragma unroll
        for (int e = 0; e < 8; e++) {
            bf0[e] = (short)f2b(wrow[ko + e]);
            bf1[e] = (short)f2b(wrow[32 + ko + e]);
        }
        bGh = bG[h];
    }
    __syncthreads();

#pragma unroll
    for (int tt = 0; tt < 4; tt++) {
        int mt = (wave << 2) + tt;
        int row = (mt << 4) + h;
        int rswz = (row & 7) << 4;
        short8 a0 = *(const short8*)(embs + (((row << 7) + (ko << 1)) ^ rswz));
        short8 a1 = *(const short8*)(embs + (((row << 7) + 64 + (ko << 1)) ^ rswz));
        f32x4 acc = {0.f, 0.f, 0.f, 0.f};
        acc = __builtin_amdgcn_mfma_f32_16x16x32_bf16(a0, bf0, acc, 0, 0, 0);
        acc = __builtin_amdgcn_mfma_f32_16x16x32_bf16(a1, bf1, acc, 0, 0, 0);

        if (h < 8) {
            int j0 = (jt << 8) + (mt << 4) + ((lane >> 4) << 2);
            u16x4 ow;
#pragma unroll
            for (int r = 0; r < 4; r++)
                ow[r] = f2h(fmaxf(acc[r] + bGh, 1e-6f) * 1024.0f);
            *(u16x4*)&outW[((size_t)((b << 3) + h) << 18) + ((size_t)i << 9) + j0] = ow;
        }
    }
}

// ---------- fused flash attention: p = w * e^(0.125*QK^T - m), O = PV/l ----------
__global__ __launch_bounds__(256) void attn_k(const u16* __restrict__ Qb,
                                              const u16* __restrict__ Kb,
                                              const u16* __restrict__ VT,
                                              const u16* __restrict__ Wp,
                                              u16* __restrict__ ATT) {
    __shared__ u16 Pl[4][16 * 68];       // per-wave P transpose, stride 68
    __shared__ float Mrg[3][64][25];     // waves 1-3 partials: m[0:4] l[4:8] o[8:24]
    const int t = threadIdx.x;
    const int wave = t >> 6, lane = t & 63;
    const int c = lane & 15, g = lane >> 4;
    const int bid = blockIdx.x;
    const int qb = bid & 31, bh = bid >> 5;
    const int b = bh >> 3, h = bh & 7;
    const int q0 = qb << 4;

    const u16* Qp = Qb + ((size_t)bh << 15);                 // [512][64]
    const u16* Kp = Kb + ((size_t)bh << 15);                 // [512][64]
    const u16* Vp = VT + ((size_t)bh << 15);                 // [64][512]
    const _Float16* Bp = (const _Float16*)Wp + ((size_t)bh << 18) + ((size_t)q0 << 9);

    short8 qf[2];
#pragma unroll
    for (int ks = 0; ks < 2; ks++)
        qf[ks] = *(const short8*)&Qp[(size_t)(q0 + c) * 64 + ks * 32 + g * 8];

    f32x4 o[4] = {};
    float m[4] = {-1e30f, -1e30f, -1e30f, -1e30f};
    float l[4] = {0.f, 0.f, 0.f, 0.f};

    for (int kt = 0; kt < 2; kt++) {
        const int k0 = ((wave << 1) + kt) << 6;
        short8 kf[4][2], vf[4][2];
#pragma unroll
        for (int jj = 0; jj < 4; jj++)
#pragma unroll
            for (int ks = 0; ks < 2; ks++) {
                kf[jj][ks] = *(const short8*)&Kp[(size_t)(k0 + jj * 16 + c) * 64 + ks * 32 + g * 8];
                vf[jj][ks] = *(const short8*)&Vp[(size_t)(jj * 16 + c) * 512 + k0 + ks * 32 + g * 8];
            }
        float wgt[4][4];
#pragma unroll
        for (int jj = 0; jj < 4; jj++)
#pragma unroll
            for (int r = 0; r < 4; r++)
                wgt[jj][r] = (float)Bp[(size_t)(g * 4 + r) * 512 + k0 + jj * 16 + c];

        f32x4 sa[4] = {};
        __builtin_amdgcn_s_setprio(1);
#pragma unroll
        for (int jj = 0; jj < 4; jj++)
#pragma unroll
            for (int ks = 0; ks < 2; ks++)
                sa[jj] = __builtin_amdgcn_mfma_f32_16x16x32_bf16(qf[ks], kf[jj][ks], sa[jj], 0, 0, 0);
        __builtin_amdgcn_s_setprio(0);

        float s[4][4];
#pragma unroll
        for (int r = 0; r < 4; r++) {
#pragma unroll
            for (int jj = 0; jj < 4; jj++)
                s[jj][r] = sa[jj][r] * 0.125f;
            float v = fmaxf(fmaxf(s[0][r], s[1][r]), fmaxf(s[2][r], s[3][r]));
#pragma unroll
            for (int off = 1; off < 16; off <<= 1)
                v = fmaxf(v, __shfl_xor(v, off));
            float mn = fmaxf(m[r], v);
            float alpha = __expf(m[r] - mn);
            m[r] = mn;
            float rs = 0.f;
#pragma unroll
            for (int jj = 0; jj < 4; jj++) {
                float p = wgt[jj][r] * __expf(s[jj][r] - mn);
                s[jj][r] = p;
                rs += p;
            }
#pragma unroll
            for (int off = 1; off < 16; off <<= 1)
                rs += __shfl_xor(rs, off);
            l[r] = l[r] * alpha + rs;
#pragma unroll
            for (int jjo = 0; jjo < 4; jjo++)
                o[jjo][r] *= alpha;
        }

#pragma unroll
        for (int jj = 0; jj < 4; jj++)
#pragma unroll
            for (int r = 0; r < 4; r++)
                Pl[wave][(g * 4 + r) * 68 + jj * 16 + c] = f2b(s[jj][r]);
        asm volatile("s_waitcnt lgkmcnt(0)" ::: "memory");
        __builtin_amdgcn_sched_barrier(0);

        short8 pa[2];
#pragma unroll
        for (int ks = 0; ks < 2; ks++)
            pa[ks] = *(const short8*)&Pl[wave][c * 68 + ks * 32 + g * 8];
        __builtin_amdgcn_s_setprio(1);
#pragma unroll
        for (int jjo = 0; jjo < 4; jjo++)
#pragma unroll
            for (int ks = 0; ks < 2; ks++)
                o[jjo] = __builtin_amdgcn_mfma_f32_16x16x32_bf16(pa[ks], vf[jjo][ks], o[jjo], 0, 0, 0);
        __builtin_amdgcn_s_setprio(0);
        __builtin_amdgcn_sched_barrier(0);
    }

    if (wave > 0) {
#pragma unroll
        for (int r = 0; r < 4; r++) {
            Mrg[wave - 1][lane][r] = m[r];
            Mrg[wave - 1][lane][4 + r] = l[r];
#pragma unroll
            for (int jjo = 0; jjo < 4; jjo++)
                Mrg[wave - 1][lane][8 + jjo * 4 + r] = o[jjo][r];
        }
    }
    __syncthreads();
    if (wave == 0) {
#pragma unroll
        for (int w = 0; w < 3; w++) {
#pragma unroll
            for (int r = 0; r < 4; r++) {
                float m1 = Mrg[w][lane][r];
                float l1 = Mrg[w][lane][4 + r];
                float mn = fmaxf(m[r], m1);
                float a0 = __expf(m[r] - mn), a1 = __expf(m1 - mn);
                m[r] = mn;
                l[r] = l[r] * a0 + l1 * a1;
#pragma unroll
                for (int jjo = 0; jjo < 4; jjo++)
                    o[jjo][r] = o[jjo][r] * a0 + Mrg[w][lane][8 + jjo * 4 + r] * a1;
            }
        }
#pragma unroll
        for (int r = 0; r < 4; r++) {
            float inv = 1.0f / l[r];
            int row = q0 + g * 4 + r;
#pragma unroll
            for (int jjo = 0; jjo < 4; jjo++)
                ATT[(size_t)(((b << 9) + row) << 9) + (h << 6) + jjo * 16 + c] = f2b(o[jjo][r] * inv);
        }
    }
}

// ---------- merged projection GEMM (bf16, global_load_lds staging) ----------
// z=0: Q, z=1: K (out [B,H,N,DK]); z=2: V (out transposed [B,H,DK,N]).
__global__ __launch_bounds__(256) void proj_k(const u16* __restrict__ Xall,
                                              const u16* __restrict__ Wall,
                                              const float* __restrict__ bq,
                                              const float* __restrict__ bk,
                                              const float* __restrict__ bv,
                                              u16* __restrict__ Qb,
                                              u16* __restrict__ Kb,
                                              u16* __restrict__ VT) {
    __shared__ u16 As[64 * 32];
    __shared__ u16 Bs[64 * 32];

    const int t = threadIdx.x;
    const int wave = t >> 6, lane = t & 63;
    const int wr = wave >> 1, wc = wave & 1;
    const int m0 = blockIdx.y * 64, n0 = blockIdx.x * 64;
    const int z = blockIdx.z;

    const u16* A  = Xall + (size_t)z * 1048576;
    const u16* Bm = Wall + (size_t)z * 262144;
    const float* bias = (z == 0) ? bq : (z == 1) ? bk : bv;
    u16* out = (z == 0) ? Qb : (z == 1) ? Kb : VT;

    f32x4 acc[2][2] = {};
    const int srow = t >> 2, scol = (t & 3) * 8;

    for (int k0 = 0; k0 < 512; k0 += 32) {
        gload_lds16(&A[(size_t)(m0 + srow) * 512 + k0 + scol], &As[t * 8]);
        gload_lds16(&Bm[(size_t)(n0 + srow) * 512 + k0 + scol], &Bs[t * 8]);
        __syncthreads();

        short8 af[2], bfr[2];
#pragma unroll
        for (int i = 0; i < 2; i++)
            af[i] = *(const short8*)&As[(wr * 32 + i * 16 + (lane & 15)) * 32 + ((lane >> 4) << 3)];
#pragma unroll
        for (int jj = 0; jj < 2; jj++)
            bfr[jj] = *(const short8*)&Bs[(wc * 32 + jj * 16 + (lane & 15)) * 32 + ((lane >> 4) << 3)];
#pragma unroll
        for (int i = 0; i < 2; i++)
#pragma unroll
            for (int jj = 0; jj < 2; jj++)
                acc[i][jj] = __builtin_amdgcn_mfma_f32_16x16x32_bf16(af[i], bfr[jj], acc[i][jj], 0, 0, 0);
        __syncthreads();
    }

#pragma unroll
    for (int i = 0; i < 2; i++) {
#pragma unroll
        for (int jj = 0; jj < 2; jj++) {
#pragma unroll
            for (int r = 0; r < 4; r++) {
                int row = m0 + wr * 32 + i * 16 + ((lane >> 4) << 2) + r;
                int col = n0 + wc * 32 + jj * 16 + (lane & 15);
                float v = acc[i][jj][r] + bias[col];
                int b = row >> 9, rr = row & 511, h = col >> 6, d = col & 63;
                if (z < 2)
                    out[(size_t)((((b << 3) + h) << 9) + rr) * 64 + d] = f2b(v);
                else
                    out[(size_t)((((b << 3) + h) << 6) + d) * 512 + rr] = f2b(v);
            }
        }
    }
}

// ---------- output GEMM: d_out[2048,512] f32 = ATT bf16 @ WOb^T + bo ----------
__global__ __launch_bounds__(256) void outg_k(const u16* __restrict__ A,
                                              const u16* __restrict__ Bm,
                                              const float* __restrict__ bias,
                                              float* __restrict__ outF) {
    __shared__ u16 As[64 * 32];
    __shared__ u16 Bs[64 * 32];

    const int t = threadIdx.x;
    const int wave = t >> 6, lane = t & 63;
    const int wr = wave >> 1, wc = wave & 1;
    const int m0 = blockIdx.y * 64, n0 = blockIdx.x * 64;

    f32x4 acc[2][2] = {};
    const int srow = t >> 2, scol = (t & 3) * 8;

    for (int k0 = 0; k0 < 512; k0 += 32) {
        gload_lds16(&A[(size_t)(m0 + srow) * 512 + k0 + scol], &As[t * 8]);
        gload_lds16(&Bm[(size_t)(n0 + srow) * 512 + k0 + scol], &Bs[t * 8]);
        __syncthreads();

        short8 af[2], bfr[2];
#pragma unroll
        for (int i = 0; i < 2; i++)
            af[i] = *(const short8*)&As[(wr * 32 + i * 16 + (lane & 15)) * 32 + ((lane >> 4) << 3)];
#pragma unroll
        for (int jj = 0; jj < 2; jj++)
            bfr[jj] = *(const short8*)&Bs[(wc * 32 + jj * 16 + (lane & 15)) * 32 + ((lane >> 4) << 3)];
#pragma unroll
        for (int i = 0; i < 2; i++)
#pragma unroll
            for (int jj = 0; jj < 2; jj++)
                acc[i][jj] = __builtin_amdgcn_mfma_f32_16x16x32_bf16(af[i], bfr[jj], acc[i][jj], 0, 0, 0);
        __syncthreads();
    }

#pragma unroll
    for (int i = 0; i < 2; i++)
#pragma unroll
        for (int jj = 0; jj < 2; jj++)
#pragma unroll
            for (int r = 0; r < 4; r++) {
                int row = m0 + wr * 32 + i * 16 + ((lane >> 4) << 2) + r;
                int col = n0 + wc * 32 + jj * 16 + (lane & 15);
                outF[((size_t)row << 9) + col] = acc[i][jj][r] + bias[col];
            }
}

// ---------- launch ----------
extern "C" void kernel_launch(void* const* d_in, const int* in_sizes, int n_in,
                              void* d_out, int out_size, void* d_ws, size_t ws_size,
                              hipStream_t stream) {
    const float* inq = (const float*)d_in[0];
    const float* ink = (const float*)d_in[1];
    const float* inv = (const float*)d_in[2];
    const float* box = (const float*)d_in[3];
    const float* Wq  = (const float*)d_in[4];
    const float* bq  = (const float*)d_in[5];
    const float* Wk  = (const float*)d_in[6];
    const float* bk  = (const float*)d_in[7];
    const float* Wv  = (const float*)d_in[8];
    const float* bv  = (const float*)d_in[9];
    const float* Wo  = (const float*)d_in[10];
    const float* bo  = (const float*)d_in[11];
    const float* WG  = (const float*)d_in[12];
    const float* bG  = (const float*)d_in[13];

    u16* base = (u16*)d_ws;
    u16* Xall = base;                    // XQ,XK,XV bf16 (3 x 1,048,576)
    u16* Wall = base + 3145728;          // WQb,WKb,WVb,WOb bf16 (4 x 262,144)
    u16* Qb   = base + 4194304;          // [B,H,N,64] bf16
    u16* Kb   = base + 5242880;          // [B,H,N,64] bf16
    u16* VT   = base + 6291456;          // [B,H,64,N] bf16
    u16* ATT  = base + 7340032;          // [B,N,512] bf16
    u16* Wp   = base + 8388608;          // [B,H,N,N] f16 geometry weights

    prep_k<<<dim3(1024, 1, 11), 256, 0, stream>>>(inq, ink, inv, Wq, Wk, Wv, Wo,
                                                  box, WG, bG, Xall, Wall, Wp);

    proj_k<<<dim3(8, 32, 3), 256, 0, stream>>>(Xall, Wall, bq, bk, bv, Qb, Kb, VT);

    attn_k<<<dim3(1024), 256, 0, stream>>>(Qb, Kb, VT, Wp, ATT);

    outg_k<<<dim3(8, 32, 1), 256, 0, stream>>>(ATT, Wall + 786432, bo, (float*)d_out);
}